// Round 5
// baseline (1396.711 us; speedup 1.0000x reference)
//
#include <hip/hip_runtime.h>
#include <math.h>

// Problem constants
#define NTOKv   8000
#define INv     300
#define HIDv    128
#define HEADSv  4
#define OUTv    128
#define CLSv    4
#define Bv      32
#define NCv     40
#define SEQv    60
#define NTv     1280   // B*NC
#define Hv      100

#define KSPLIT  5
#define KLEN    1600    // 8000 / KSPLIT

typedef __attribute__((ext_vector_type(8))) short bf16x8;
typedef __attribute__((ext_vector_type(4))) float f32x4;
typedef __attribute__((ext_vector_type(8))) float f32x8;

// ---------------- ordered-float encoding for atomicMax on unsigned ----------
__device__ __forceinline__ unsigned fenc(float f) {
    unsigned u = __float_as_uint(f);
    return (u & 0x80000000u) ? ~u : (u | 0x80000000u);
}
__device__ __forceinline__ float fdec(unsigned u) {
    return (u & 0x80000000u) ? __uint_as_float(u ^ 0x80000000u) : __uint_as_float(~u);
}

__device__ __forceinline__ short f2bf(float f) {
    unsigned u = __float_as_uint(f);
    u = u + 0x7FFFu + ((u >> 16) & 1u);   // RNE
    return (short)(u >> 16);
}

// ---------------- generic tiled fp32 GEMM: C = A(MxK) @ B(KxN) (+bias)(+relu)
#define BM 64
#define BN 64
#define BK 16
__global__ __launch_bounds__(256) void gemm_nn(const float* __restrict__ A,
                                               const float* __restrict__ B,
                                               const float* __restrict__ bias,
                                               float* __restrict__ C,
                                               int M, int N, int K, int relu) {
    __shared__ float As[BK][BM + 4];
    __shared__ float Bs[BK][BN + 4];
    int tid = threadIdx.x;
    int bn = blockIdx.x * BN, bm = blockIdx.y * BM;
    int tx = tid & 15, ty = tid >> 4;
    float acc[4][4] = {};
    for (int k0 = 0; k0 < K; k0 += BK) {
#pragma unroll
        for (int i = 0; i < 4; ++i) {
            int t = tid + i * 256;
            int m = t >> 4, kk = t & 15;
            float v = 0.f;
            if ((bm + m) < M && (k0 + kk) < K) v = A[(size_t)(bm + m) * K + k0 + kk];
            As[kk][m] = v;
        }
#pragma unroll
        for (int i = 0; i < 4; ++i) {
            int t = tid + i * 256;
            int kk = t >> 6, n = t & 63;
            float v = 0.f;
            if ((k0 + kk) < K && (bn + n) < N) v = B[(size_t)(k0 + kk) * N + bn + n];
            Bs[kk][n] = v;
        }
        __syncthreads();
#pragma unroll
        for (int kk = 0; kk < BK; ++kk) {
            float a[4], b[4];
#pragma unroll
            for (int r = 0; r < 4; ++r) a[r] = As[kk][ty * 4 + r];
#pragma unroll
            for (int c = 0; c < 4; ++c) b[c] = Bs[kk][tx * 4 + c];
#pragma unroll
            for (int r = 0; r < 4; ++r)
#pragma unroll
                for (int c = 0; c < 4; ++c) acc[r][c] = fmaf(a[r], b[c], acc[r][c]);
        }
        __syncthreads();
    }
#pragma unroll
    for (int r = 0; r < 4; ++r) {
        int m = bm + ty * 4 + r;
        if (m >= M) continue;
#pragma unroll
        for (int c = 0; c < 4; ++c) {
            int n = bn + tx * 4 + c;
            if (n >= N) continue;
            float v = acc[r][c];
            if (bias) v += bias[n];
            if (relu) v = fmaxf(v, 0.f);
            C[(size_t)m * N + n] = v;
        }
    }
}

// C = A(MxK) @ B(NxK)^T (+bias over N)
__global__ __launch_bounds__(256) void gemm_nt(const float* __restrict__ A,
                                               const float* __restrict__ B,
                                               const float* __restrict__ bias,
                                               float* __restrict__ C,
                                               int M, int N, int K) {
    __shared__ float As[BK][BM + 4];
    __shared__ float Bs[BK][BN + 4];
    int tid = threadIdx.x;
    int bn = blockIdx.x * BN, bm = blockIdx.y * BM;
    int tx = tid & 15, ty = tid >> 4;
    float acc[4][4] = {};
    for (int k0 = 0; k0 < K; k0 += BK) {
#pragma unroll
        for (int i = 0; i < 4; ++i) {
            int t = tid + i * 256;
            int m = t >> 4, kk = t & 15;
            float v = 0.f;
            if ((bm + m) < M && (k0 + kk) < K) v = A[(size_t)(bm + m) * K + k0 + kk];
            As[kk][m] = v;
        }
#pragma unroll
        for (int i = 0; i < 4; ++i) {
            int t = tid + i * 256;
            int n = t >> 4, kk = t & 15;
            float v = 0.f;
            if ((bn + n) < N && (k0 + kk) < K) v = B[(size_t)(bn + n) * K + k0 + kk];
            Bs[kk][n] = v;
        }
        __syncthreads();
#pragma unroll
        for (int kk = 0; kk < BK; ++kk) {
            float a[4], b[4];
#pragma unroll
            for (int r = 0; r < 4; ++r) a[r] = As[kk][ty * 4 + r];
#pragma unroll
            for (int c = 0; c < 4; ++c) b[c] = Bs[kk][tx * 4 + c];
#pragma unroll
            for (int r = 0; r < 4; ++r)
#pragma unroll
                for (int c = 0; c < 4; ++c) acc[r][c] = fmaf(a[r], b[c], acc[r][c]);
        }
        __syncthreads();
    }
#pragma unroll
    for (int r = 0; r < 4; ++r) {
        int m = bm + ty * 4 + r;
        if (m >= M) continue;
#pragma unroll
        for (int c = 0; c < 4; ++c) {
            int n = bn + tx * 4 + c;
            if (n >= N) continue;
            float v = acc[r][c];
            if (bias) v += bias[n];
            C[(size_t)m * N + n] = v;
        }
    }
}

// ---------------- pack B (KxN=128 fp32, row-major) -> bf16 frag layout -------
__global__ __launch_bounds__(256) void pack_b_kernel(const float* __restrict__ B,
                                                     short* __restrict__ out) {
    __shared__ float sh[32 * 129];
    int kc = blockIdx.x;
    int tid = threadIdx.x;
    const float* src = B + (size_t)kc * 4096;
    for (int i = tid; i < 4096; i += 256)
        sh[(i >> 7) * 129 + (i & 127)] = src[i];
    __syncthreads();
    short* op = out + (size_t)kc * 4096;
    for (int i = tid; i < 4096; i += 256) {
        int n = i >> 5, r = i & 31;
        op[i] = f2bf(sh[r * 129 + n]);
    }
}

// ---------------- MFMA GEMM v3: K-split, atomic accumulate ------------------
// grid (M/16, KSPLIT). 16 rows/block, 4 waves each own a 32-col strip.
// Each block covers K range [by*KLEN, +KLEN), atomicAdds partial tile into C.
__global__ __launch_bounds__(256) void gcn_mfma(const float* __restrict__ A,
                                                const short* __restrict__ Bpack,
                                                float* __restrict__ C,
                                                int K) {
    int tid = threadIdx.x;
    int lane = tid & 63;
    int wc = tid >> 6;          // wave -> 32-col strip
    int quad = lane >> 4;
    int nl = lane & 15;
    int mrow = blockIdx.x * 16 + nl;
    int kbase = blockIdx.y * KLEN;

    const float* ap = A + (size_t)mrow * K + kbase + quad * 8;
    const short* bp = Bpack + ((size_t)(kbase >> 5)) * 4096
                      + ((size_t)(wc * 32 + nl) << 5) + quad * 8;
    const int NP = KLEN >> 6;   // 25 pairs of 32-wide chunks

    f32x4 acc0 = {0.f, 0.f, 0.f, 0.f};
    f32x4 acc1 = {0.f, 0.f, 0.f, 0.f};

    auto loadA = [&](int p, int h) {
        return *(const f32x8*)(ap + (size_t)(2 * p + h) * 32);
    };
    auto loadB = [&](int p, int h, int t) {
        return *(const bf16x8*)(bp + (size_t)(2 * p + h) * 4096 + t * 512);
    };

    f32x8 a0A = loadA(0, 0), a0B = loadA(0, 1);
    f32x8 a1A = loadA(1, 0), a1B = loadA(1, 1);
    bf16x8 b00 = loadB(0, 0, 0), b01 = loadB(0, 0, 1);
    bf16x8 b10 = loadB(0, 1, 0), b11 = loadB(0, 1, 1);

    for (int p = 0; p < NP; ++p) {
        int pn2 = p + 2 < NP ? p + 2 : NP - 1;
        int pn1 = p + 1 < NP ? p + 1 : NP - 1;
        f32x8 a2A = loadA(pn2, 0), a2B = loadA(pn2, 1);
        bf16x8 nb00 = loadB(pn1, 0, 0), nb01 = loadB(pn1, 0, 1);
        bf16x8 nb10 = loadB(pn1, 1, 0), nb11 = loadB(pn1, 1, 1);

        bf16x8 af;
#pragma unroll
        for (int i = 0; i < 8; ++i) af[i] = f2bf(a0A[i]);
        acc0 = __builtin_amdgcn_mfma_f32_16x16x32_bf16(af, b00, acc0, 0, 0, 0);
        acc1 = __builtin_amdgcn_mfma_f32_16x16x32_bf16(af, b01, acc1, 0, 0, 0);
#pragma unroll
        for (int i = 0; i < 8; ++i) af[i] = f2bf(a0B[i]);
        acc0 = __builtin_amdgcn_mfma_f32_16x16x32_bf16(af, b10, acc0, 0, 0, 0);
        acc1 = __builtin_amdgcn_mfma_f32_16x16x32_bf16(af, b11, acc1, 0, 0, 0);

        a0A = a1A; a0B = a1B; a1A = a2A; a1B = a2B;
        b00 = nb00; b01 = nb01; b10 = nb10; b11 = nb11;
    }

    int rbase = blockIdx.x * 16 + quad * 4;
    int cbase = wc * 32 + nl;
#pragma unroll
    for (int t = 0; t < 2; ++t) {
        int col = cbase + t * 16;
        f32x4 a = (t == 0) ? acc0 : acc1;
#pragma unroll
        for (int reg = 0; reg < 4; ++reg)
            atomicAdd(&C[(size_t)(rbase + reg) * 128 + col], a[reg]);
    }
}

// ---------------- GAT helper kernels ----------------
__global__ void eler_kernel(const float* __restrict__ z, const float* __restrict__ al,
                            const float* __restrict__ ar, float* __restrict__ el,
                            float* __restrict__ er, int nNodes, int heads, int dim) {
    int idx = blockIdx.x * blockDim.x + threadIdx.x;
    if (idx >= nNodes * heads) return;
    int n = idx / heads, h = idx % heads;
    const float* zp = z + ((size_t)n * heads + h) * dim;
    const float* alp = al + (size_t)h * dim;
    const float* arp = ar + (size_t)h * dim;
    float sl = 0.f, sr = 0.f;
    for (int d = 0; d < dim; ++d) {
        sl = fmaf(zp[d], alp[d], sl);
        sr = fmaf(zp[d], arp[d], sr);
    }
    el[idx] = sl;
    er[idx] = sr;
}

__global__ void edge_max_kernel(const int* __restrict__ src, const int* __restrict__ dst,
                                const float* __restrict__ el, const float* __restrict__ er,
                                float* __restrict__ ebuf, unsigned* __restrict__ mkey,
                                int E, int heads) {
    int idx = blockIdx.x * blockDim.x + threadIdx.x;
    if (idx >= E * heads) return;
    int e = idx / heads, h = idx % heads;
    int s = src[e], d = dst[e];
    float x = el[s * heads + h] + er[d * heads + h];
    x = (x > 0.f) ? x : 0.2f * x;
    ebuf[idx] = x;
    atomicMax(&mkey[d * heads + h], fenc(x));
}

__global__ void edge_exp_kernel(const int* __restrict__ dst, float* __restrict__ ebuf,
                                const unsigned* __restrict__ mkey, float* __restrict__ ssum,
                                int E, int heads) {
    int idx = blockIdx.x * blockDim.x + threadIdx.x;
    if (idx >= E * heads) return;
    int e = idx / heads, h = idx % heads;
    int d = dst[e];
    float m = fdec(mkey[d * heads + h]);
    float ex = expf(ebuf[idx] - m);
    ebuf[idx] = ex;
    atomicAdd(&ssum[d * heads + h], ex);
}

// agg[dst] += z[src] * (ex / s[dst])   (coef fused)
__global__ void edge_msg_kernel(const int* __restrict__ src, const int* __restrict__ dst,
                                const float* __restrict__ z, const float* __restrict__ ebuf,
                                const float* __restrict__ ssum,
                                float* __restrict__ agg, int E, int heads, int dim) {
    int idx = blockIdx.x * blockDim.x + threadIdx.x;
    int HD = heads * dim;
    if (idx >= E * HD) return;
    int e = idx / HD;
    int j = idx % HD;
    int h = j / dim;
    int d = dst[e];
    float coef = ebuf[e * heads + h] / ssum[d * heads + h];
    float v = z[(size_t)src[e] * HD + j] * coef;
    atomicAdd(&agg[(size_t)d * HD + j], v);
}

__global__ void bias_act_kernel(const float* __restrict__ in, const float* __restrict__ bias,
                                float* __restrict__ out, int n, int cols, int relu) {
    int idx = blockIdx.x * blockDim.x + threadIdx.x;
    if (idx >= n) return;
    float v = in[idx] + bias[idx % cols];
    if (relu) v = fmaxf(v, 0.f);
    out[idx] = v;
}

// ---------------- gather/concat ----------------
__global__ void gather_concat_kernel(const float* __restrict__ tok, const float* __restrict__ inst,
                                     const int* __restrict__ lids, const int* __restrict__ gids,
                                     float* __restrict__ xcat) {
    int bs = blockIdx.x;
    int j = threadIdx.x;
    int g = gids[bs];
    int b = bs / SEQv;
    int l = lids[bs];
    float v;
    if (j < 128) v = tok[(size_t)g * 128 + j];
    else v = inst[(size_t)(b * NCv + l) * 128 + (j - 128)];
    xcat[(size_t)bs * 256 + j] = v;
}

// ---------------- LSTM recurrence v2: Whh rows in registers ----------------
__global__ __launch_bounds__(512) void lstm2_kernel(const float* __restrict__ xW,
                                                    const float* __restrict__ Whh_f,
                                                    const float* __restrict__ Whh_b,
                                                    float* __restrict__ y,
                                                    float* __restrict__ hidden,
                                                    int write_y) {
    int b = blockIdx.x;
    int dir = blockIdx.y;
    int t = threadIdx.x;
    const float* Whh = dir ? Whh_b : Whh_f;
    const float* xw = xW + ((size_t)dir * Bv * SEQv + (size_t)b * SEQv) * 400;

    __shared__ float hsh[104];
    __shared__ float gsh[400];

    float w[100];
    if (t < 400) {
        const float* wr = Whh + (size_t)t * 100;
#pragma unroll
        for (int j = 0; j < 100; j += 4) {
            float4 v = *(const float4*)(wr + j);
            w[j] = v.x; w[j + 1] = v.y; w[j + 2] = v.z; w[j + 3] = v.w;
        }
    }
    if (t < 104) hsh[t] = 0.f;
    float c = 0.f;
    __syncthreads();

    for (int it = 0; it < SEQv; ++it) {
        int tt = dir ? (SEQv - 1 - it) : it;
        if (t < 400) {
            float a0 = 0.f, a1 = 0.f, a2 = 0.f, a3 = 0.f;
#pragma unroll
            for (int k = 0; k < 100; k += 4) {
                a0 = fmaf(w[k], hsh[k], a0);
                a1 = fmaf(w[k + 1], hsh[k + 1], a1);
                a2 = fmaf(w[k + 2], hsh[k + 2], a2);
                a3 = fmaf(w[k + 3], hsh[k + 3], a3);
            }
            gsh[t] = xw[tt * 400 + t] + ((a0 + a1) + (a2 + a3));
        }
        __syncthreads();
        if (t < Hv) {
            float gi = gsh[t], gf = gsh[Hv + t], gg = gsh[2 * Hv + t], go = gsh[3 * Hv + t];
            float si = 1.f / (1.f + expf(-gi));
            float sf = 1.f / (1.f + expf(-gf));
            float so = 1.f / (1.f + expf(-go));
            float tg = tanhf(gg);
            c = sf * c + si * tg;
            float h = so * tanhf(c);
            hsh[t] = h;
            if (write_y) y[((size_t)b * SEQv + tt) * 200 + dir * Hv + t] = h;
        }
        __syncthreads();
    }
    if (!write_y && t < Hv) hidden[b * 200 + dir * Hv + t] = hsh[t];
}

// ---------------- final FC ----------------
__global__ void fc_kernel(const float* __restrict__ hidden, const float* __restrict__ W,
                          const float* __restrict__ bias, float* __restrict__ out) {
    int idx = threadIdx.x;
    if (idx >= Bv * CLSv) return;
    int b = idx >> 2, c = idx & 3;
    float s = bias[c];
    for (int j = 0; j < 200; ++j) s = fmaf(hidden[b * 200 + j], W[j * 4 + c], s);
    out[idx] = s;
}

// ============================================================================
extern "C" void kernel_launch(void* const* d_in, const int* in_sizes, int n_in,
                              void* d_out, int out_size, void* d_ws, size_t ws_size,
                              hipStream_t stream) {
    const float* emb      = (const float*)d_in[0];
    const float* tg       = (const float*)d_in[1];
    const float* tokemb   = (const float*)d_in[2];
    const float* gcn_W1   = (const float*)d_in[3];
    const float* gcn_b1   = (const float*)d_in[4];
    const float* gcn_W2   = (const float*)d_in[5];
    const float* gcn_b2   = (const float*)d_in[6];
    const float* gat1_W   = (const float*)d_in[7];
    const float* gat1_al  = (const float*)d_in[8];
    const float* gat1_ar  = (const float*)d_in[9];
    const float* gat1_b   = (const float*)d_in[10];
    const float* gat2_W   = (const float*)d_in[11];
    const float* gat2_al  = (const float*)d_in[12];
    const float* gat2_ar  = (const float*)d_in[13];
    const float* gat2_b   = (const float*)d_in[14];
    const float* l0f_Wih  = (const float*)d_in[15];
    const float* l0f_Whh  = (const float*)d_in[16];
    const float* l0f_b    = (const float*)d_in[17];
    const float* l0b_Wih  = (const float*)d_in[18];
    const float* l0b_Whh  = (const float*)d_in[19];
    const float* l0b_b    = (const float*)d_in[20];
    const float* l1f_Wih  = (const float*)d_in[21];
    const float* l1f_Whh  = (const float*)d_in[22];
    const float* l1f_b    = (const float*)d_in[23];
    const float* l1b_Wih  = (const float*)d_in[24];
    const float* l1b_Whh  = (const float*)d_in[25];
    const float* l1b_b    = (const float*)d_in[26];
    const float* fc_W     = (const float*)d_in[27];
    const float* fc_b     = (const float*)d_in[28];
    const int*   src      = (const int*)d_in[29];
    const int*   dst      = (const int*)d_in[30];
    const int*   lids     = (const int*)d_in[31];
    const int*   gids     = (const int*)d_in[32];
    const int E = in_sizes[29];   // 11520

    float* ws = (float*)d_ws;
    size_t off = 0;
    auto alloc = [&](size_t n) { float* p = ws + off; off += n; return p; };

    // ---- zero-initialized region (single memset) ----
    float* m1   = alloc((size_t)NTv * HEADSv);
    float* s1   = alloc((size_t)NTv * HEADSv);
    float* agg1 = alloc((size_t)NTv * 512);
    float* m2   = alloc(NTv);
    float* s2   = alloc(NTv);
    float* agg2 = alloc((size_t)NTv * 128);
    float* T    = alloc((size_t)NTOKv * 128);   // atomic accumulate targets
    float* tok  = alloc((size_t)NTOKv * 128);
    size_t zeroFloats = off;

    float* z1   = alloc((size_t)NTv * 512);
    float* el1  = alloc((size_t)NTv * HEADSv);
    float* er1  = alloc((size_t)NTv * HEADSv);
    float* ebuf = alloc((size_t)E * HEADSv);
    float* h1   = alloc((size_t)NTv * 512);
    float* z2   = alloc((size_t)NTv * 128);
    float* el2  = alloc(NTv);
    float* er2  = alloc(NTv);
    float* inst = alloc((size_t)NTv * 128);
    float* P    = alloc((size_t)NTOKv * 128);
    float* Q    = alloc((size_t)NTOKv * 128);
    float* xcat = alloc((size_t)Bv * SEQv * 256);
    float* xw0  = alloc((size_t)2 * Bv * SEQv * 400);
    float* y    = alloc((size_t)Bv * SEQv * 200);
    float* xw1  = alloc((size_t)2 * Bv * SEQv * 400);
    float* hidden = alloc((size_t)Bv * 200);
    short* Ppack = (short*)alloc((size_t)NTOKv * 128 / 2);
    short* Qpack = (short*)alloc((size_t)NTOKv * 128 / 2);
    (void)ws_size;

    hipMemsetAsync(d_ws, 0, zeroFloats * sizeof(float), stream);

    // ================= GAT layer 1 =================
    {
        dim3 g(512 / BN, NTv / BM);
        gemm_nn<<<g, 256, 0, stream>>>(emb, gat1_W, nullptr, z1, NTv, 512, INv, 0);
    }
    eler_kernel<<<(NTv * HEADSv + 255) / 256, 256, 0, stream>>>(z1, gat1_al, gat1_ar, el1, er1, NTv, HEADSv, 128);
    {
        int n = E * HEADSv, blocks = (n + 255) / 256;
        edge_max_kernel<<<blocks, 256, 0, stream>>>(src, dst, el1, er1, ebuf, (unsigned*)m1, E, HEADSv);
        edge_exp_kernel<<<blocks, 256, 0, stream>>>(dst, ebuf, (const unsigned*)m1, s1, E, HEADSv);
        int n2 = E * 512;
        edge_msg_kernel<<<(n2 + 255) / 256, 256, 0, stream>>>(src, dst, z1, ebuf, s1, agg1, E, HEADSv, 128);
    }
    bias_act_kernel<<<(NTv * 512 + 255) / 256, 256, 0, stream>>>(agg1, gat1_b, h1, NTv * 512, 512, 1);

    // ================= GAT layer 2 =================
    {
        dim3 g(128 / BN, NTv / BM);
        gemm_nn<<<g, 256, 0, stream>>>(h1, gat2_W, nullptr, z2, NTv, 128, 512, 0);
    }
    eler_kernel<<<(NTv + 255) / 256, 256, 0, stream>>>(z2, gat2_al, gat2_ar, el2, er2, NTv, 1, 128);
    {
        int n = E, blocks = (n + 255) / 256;
        edge_max_kernel<<<blocks, 256, 0, stream>>>(src, dst, el2, er2, ebuf, (unsigned*)m2, E, 1);
        edge_exp_kernel<<<blocks, 256, 0, stream>>>(dst, ebuf, (const unsigned*)m2, s2, E, 1);
        int n2 = E * 128;
        edge_msg_kernel<<<(n2 + 255) / 256, 256, 0, stream>>>(src, dst, z2, ebuf, s2, agg2, E, 1, 128);
    }
    bias_act_kernel<<<(NTv * 128 + 255) / 256, 256, 0, stream>>>(agg2, gat2_b, inst, NTv * 128, 128, 0);

    // ================= GCN (token graph) — MFMA K-split path =================
    {
        dim3 g(128 / BN, NTOKv / BM);
        dim3 gg(NTOKv / 16, KSPLIT);
        gemm_nn<<<g, 256, 0, stream>>>(tokemb, gcn_W1, nullptr, P, NTOKv, 128, INv, 0);
        pack_b_kernel<<<NTOKv / 32, 256, 0, stream>>>(P, Ppack);
        gcn_mfma<<<gg, 256, 0, stream>>>(tg, Ppack, T, NTOKv);
        bias_act_kernel<<<(NTOKv * 128 + 255) / 256, 256, 0, stream>>>(T, gcn_b1, T, NTOKv * 128, 128, 1);
        gemm_nn<<<g, 256, 0, stream>>>(T, gcn_W2, nullptr, Q, NTOKv, 128, 128, 0);
        pack_b_kernel<<<NTOKv / 32, 256, 0, stream>>>(Q, Qpack);
        gcn_mfma<<<gg, 256, 0, stream>>>(tg, Qpack, tok, NTOKv);
        bias_act_kernel<<<(NTOKv * 128 + 255) / 256, 256, 0, stream>>>(tok, gcn_b2, tok, NTOKv * 128, 128, 0);
    }

    // ================= gather/concat =================
    gather_concat_kernel<<<Bv * SEQv, 256, 0, stream>>>(tok, inst, lids, gids, xcat);

    // ================= LSTM layer 0 =================
    {
        dim3 g((400 + BN - 1) / BN, (Bv * SEQv) / BM);
        gemm_nt<<<g, 256, 0, stream>>>(xcat, l0f_Wih, l0f_b, xw0, Bv * SEQv, 400, 256);
        gemm_nt<<<g, 256, 0, stream>>>(xcat, l0b_Wih, l0b_b, xw0 + (size_t)Bv * SEQv * 400, Bv * SEQv, 400, 256);
    }
    {
        dim3 g(Bv, 2);
        lstm2_kernel<<<g, 512, 0, stream>>>(xw0, l0f_Whh, l0b_Whh, y, nullptr, 1);
    }

    // ================= LSTM layer 1 =================
    {
        dim3 g((400 + BN - 1) / BN, (Bv * SEQv) / BM);
        gemm_nt<<<g, 256, 0, stream>>>(y, l1f_Wih, l1f_b, xw1, Bv * SEQv, 400, 200);
        gemm_nt<<<g, 256, 0, stream>>>(y, l1b_Wih, l1b_b, xw1 + (size_t)Bv * SEQv * 400, Bv * SEQv, 400, 200);
    }
    {
        dim3 g(Bv, 2);
        lstm2_kernel<<<g, 512, 0, stream>>>(xw1, l1f_Whh, l1b_Whh, nullptr, hidden, 0);
    }

    // ================= FC head =================
    fc_kernel<<<1, 128, 0, stream>>>(hidden, fc_W, fc_b, (float*)d_out);
}

// Round 6
// 1280.031 us; speedup vs baseline: 1.0912x; 1.0912x over previous
//
#include <hip/hip_runtime.h>
#include <math.h>

// Problem constants
#define NTOKv   8000
#define INv     300
#define HIDv    128
#define HEADSv  4
#define OUTv    128
#define CLSv    4
#define Bv      32
#define NCv     40
#define SEQv    60
#define NTv     1280   // B*NC
#define Hv      100

#define KSPLIT  5
#define KLEN    1600            // 8000 / KSPLIT
#define NCHUNK  (KLEN / 32)     // 50

typedef __attribute__((ext_vector_type(8))) short bf16x8;
typedef __attribute__((ext_vector_type(4))) float f32x4;
typedef __attribute__((ext_vector_type(8))) float f32x8;

// ---------------- ordered-float encoding for atomicMax on unsigned ----------
__device__ __forceinline__ unsigned fenc(float f) {
    unsigned u = __float_as_uint(f);
    return (u & 0x80000000u) ? ~u : (u | 0x80000000u);
}
__device__ __forceinline__ float fdec(unsigned u) {
    return (u & 0x80000000u) ? __uint_as_float(u ^ 0x80000000u) : __uint_as_float(~u);
}

__device__ __forceinline__ short f2bf(float f) {
    unsigned u = __float_as_uint(f);
    u = u + 0x7FFFu + ((u >> 16) & 1u);   // RNE
    return (short)(u >> 16);
}

// ---------------- generic tiled fp32 GEMM: C = A(MxK) @ B(KxN) (+bias)(+relu)
#define BM 64
#define BN 64
#define BK 16
__global__ __launch_bounds__(256) void gemm_nn(const float* __restrict__ A,
                                               const float* __restrict__ B,
                                               const float* __restrict__ bias,
                                               float* __restrict__ C,
                                               int M, int N, int K, int relu) {
    __shared__ float As[BK][BM + 4];
    __shared__ float Bs[BK][BN + 4];
    int tid = threadIdx.x;
    int bn = blockIdx.x * BN, bm = blockIdx.y * BM;
    int tx = tid & 15, ty = tid >> 4;
    float acc[4][4] = {};
    for (int k0 = 0; k0 < K; k0 += BK) {
#pragma unroll
        for (int i = 0; i < 4; ++i) {
            int t = tid + i * 256;
            int m = t >> 4, kk = t & 15;
            float v = 0.f;
            if ((bm + m) < M && (k0 + kk) < K) v = A[(size_t)(bm + m) * K + k0 + kk];
            As[kk][m] = v;
        }
#pragma unroll
        for (int i = 0; i < 4; ++i) {
            int t = tid + i * 256;
            int kk = t >> 6, n = t & 63;
            float v = 0.f;
            if ((k0 + kk) < K && (bn + n) < N) v = B[(size_t)(k0 + kk) * N + bn + n];
            Bs[kk][n] = v;
        }
        __syncthreads();
#pragma unroll
        for (int kk = 0; kk < BK; ++kk) {
            float a[4], b[4];
#pragma unroll
            for (int r = 0; r < 4; ++r) a[r] = As[kk][ty * 4 + r];
#pragma unroll
            for (int c = 0; c < 4; ++c) b[c] = Bs[kk][tx * 4 + c];
#pragma unroll
            for (int r = 0; r < 4; ++r)
#pragma unroll
                for (int c = 0; c < 4; ++c) acc[r][c] = fmaf(a[r], b[c], acc[r][c]);
        }
        __syncthreads();
    }
#pragma unroll
    for (int r = 0; r < 4; ++r) {
        int m = bm + ty * 4 + r;
        if (m >= M) continue;
#pragma unroll
        for (int c = 0; c < 4; ++c) {
            int n = bn + tx * 4 + c;
            if (n >= N) continue;
            float v = acc[r][c];
            if (bias) v += bias[n];
            if (relu) v = fmaxf(v, 0.f);
            C[(size_t)m * N + n] = v;
        }
    }
}

// C = A(MxK) @ B(NxK)^T (+bias over N)
__global__ __launch_bounds__(256) void gemm_nt(const float* __restrict__ A,
                                               const float* __restrict__ B,
                                               const float* __restrict__ bias,
                                               float* __restrict__ C,
                                               int M, int N, int K) {
    __shared__ float As[BK][BM + 4];
    __shared__ float Bs[BK][BN + 4];
    int tid = threadIdx.x;
    int bn = blockIdx.x * BN, bm = blockIdx.y * BM;
    int tx = tid & 15, ty = tid >> 4;
    float acc[4][4] = {};
    for (int k0 = 0; k0 < K; k0 += BK) {
#pragma unroll
        for (int i = 0; i < 4; ++i) {
            int t = tid + i * 256;
            int m = t >> 4, kk = t & 15;
            float v = 0.f;
            if ((bm + m) < M && (k0 + kk) < K) v = A[(size_t)(bm + m) * K + k0 + kk];
            As[kk][m] = v;
        }
#pragma unroll
        for (int i = 0; i < 4; ++i) {
            int t = tid + i * 256;
            int n = t >> 4, kk = t & 15;
            float v = 0.f;
            if ((bn + n) < N && (k0 + kk) < K) v = B[(size_t)(bn + n) * K + k0 + kk];
            Bs[kk][n] = v;
        }
        __syncthreads();
#pragma unroll
        for (int kk = 0; kk < BK; ++kk) {
            float a[4], b[4];
#pragma unroll
            for (int r = 0; r < 4; ++r) a[r] = As[kk][ty * 4 + r];
#pragma unroll
            for (int c = 0; c < 4; ++c) b[c] = Bs[kk][tx * 4 + c];
#pragma unroll
            for (int r = 0; r < 4; ++r)
#pragma unroll
                for (int c = 0; c < 4; ++c) acc[r][c] = fmaf(a[r], b[c], acc[r][c]);
        }
        __syncthreads();
    }
#pragma unroll
    for (int r = 0; r < 4; ++r) {
        int m = bm + ty * 4 + r;
        if (m >= M) continue;
#pragma unroll
        for (int c = 0; c < 4; ++c) {
            int n = bn + tx * 4 + c;
            if (n >= N) continue;
            float v = acc[r][c];
            if (bias) v += bias[n];
            C[(size_t)m * N + n] = v;
        }
    }
}

// ---------------- pack B (KxN=128 fp32, row-major) -> bf16 frag layout -------
// out[(kc*128 + n)*32 + r] = bf16(B[kc*32 + r][n])
__global__ __launch_bounds__(256) void pack_b_kernel(const float* __restrict__ B,
                                                     short* __restrict__ out) {
    __shared__ float sh[32 * 129];
    int kc = blockIdx.x;
    int tid = threadIdx.x;
    const float* src = B + (size_t)kc * 4096;
    for (int i = tid; i < 4096; i += 256)
        sh[(i >> 7) * 129 + (i & 127)] = src[i];
    __syncthreads();
    short* op = out + (size_t)kc * 4096;
    for (int i = tid; i < 4096; i += 256) {
        int n = i >> 5, r = i & 31;
        op[i] = f2bf(sh[r * 129 + n]);
    }
}

// ---------------- pack A (tg, 8000x8000 fp32) -> bf16 A-frag layout ----------
// out[((k/32)*8000 + m)*32 + (k%32)] = bf16(A[m][k]); 8 k's per thread.
__global__ __launch_bounds__(256) void pack_a_kernel(const float* __restrict__ A,
                                                     short* __restrict__ out) {
    size_t gid = (size_t)blockIdx.x * 256 + threadIdx.x;   // 8M total
    int q = (int)(gid & 3);
    size_t rest = gid >> 2;
    int m = (int)(rest % 8000);
    int kc = (int)(rest / 8000);
    const float* src = A + (size_t)m * 8000 + kc * 32 + q * 8;
    f32x8 v = *(const f32x8*)src;
    bf16x8 o;
#pragma unroll
    for (int i = 0; i < 8; ++i) o[i] = f2bf(v[i]);
    *(bf16x8*)(out + ((size_t)kc * 8000 + m) * 32 + q * 8) = o;
}

// ---------------- MFMA GEMM v5: pre-packed bf16 A and B, K-split atomics -----
// grid (250, KSPLIT). 32 rows x 128 cols per block; 4 waves = 4 col strips.
// Frag layouts (verified): A[m=lane&15][k=quad*8+j], B[k][n=lane&15],
// C/D col=lane&15, row=quad*4+reg.
__global__ __launch_bounds__(256) void gcn_mfma5(const short* __restrict__ Apack,
                                                 const short* __restrict__ Bpack,
                                                 float* __restrict__ C) {
    int tid = threadIdx.x;
    int lane = tid & 63;
    int wc = tid >> 6;
    int quad = lane >> 4;
    int nl = lane & 15;
    int m0 = blockIdx.x * 32;
    int kc0 = blockIdx.y * NCHUNK;

    const short* apA = Apack + ((size_t)kc0 * 8000 + m0 + nl) * 32 + quad * 8;
    const short* apB = apA + 16 * 32;                       // rows +16
    const short* bp0 = Bpack + ((size_t)kc0 * 128 + wc * 32 + nl) * 32 + quad * 8;
    const short* bp1 = bp0 + 16 * 32;                       // cols +16

    f32x4 acc00 = {0.f, 0.f, 0.f, 0.f};
    f32x4 acc01 = acc00, acc10 = acc00, acc11 = acc00;

    auto lA0 = [&](int c) { return *(const bf16x8*)(apA + (size_t)c * 256000); };
    auto lA1 = [&](int c) { return *(const bf16x8*)(apB + (size_t)c * 256000); };
    auto lB0 = [&](int c) { return *(const bf16x8*)(bp0 + (size_t)c * 4096); };
    auto lB1 = [&](int c) { return *(const bf16x8*)(bp1 + (size_t)c * 4096); };

    bf16x8 a00 = lA0(0), a10 = lA1(0), b00 = lB0(0), b10 = lB1(0);
    bf16x8 a01 = lA0(1), a11 = lA1(1), b01 = lB0(1), b11 = lB1(1);

    for (int c = 0; c < NCHUNK; ++c) {
        int cn = c + 2 < NCHUNK ? c + 2 : NCHUNK - 1;
        bf16x8 na0 = lA0(cn), na1 = lA1(cn), nb0 = lB0(cn), nb1 = lB1(cn);

        acc00 = __builtin_amdgcn_mfma_f32_16x16x32_bf16(a00, b00, acc00, 0, 0, 0);
        acc01 = __builtin_amdgcn_mfma_f32_16x16x32_bf16(a00, b10, acc01, 0, 0, 0);
        acc10 = __builtin_amdgcn_mfma_f32_16x16x32_bf16(a10, b00, acc10, 0, 0, 0);
        acc11 = __builtin_amdgcn_mfma_f32_16x16x32_bf16(a10, b10, acc11, 0, 0, 0);

        a00 = a01; a10 = a11; b00 = b01; b10 = b11;
        a01 = na0; a11 = na1; b01 = nb0; b11 = nb1;
    }

    int rb0 = m0 + quad * 4;
    int rb1 = rb0 + 16;
    int c0 = wc * 32 + nl;
    int c1 = c0 + 16;
#pragma unroll
    for (int reg = 0; reg < 4; ++reg) {
        atomicAdd(&C[(size_t)(rb0 + reg) * 128 + c0], acc00[reg]);
        atomicAdd(&C[(size_t)(rb0 + reg) * 128 + c1], acc01[reg]);
        atomicAdd(&C[(size_t)(rb1 + reg) * 128 + c0], acc10[reg]);
        atomicAdd(&C[(size_t)(rb1 + reg) * 128 + c1], acc11[reg]);
    }
}

// ---------------- MFMA GEMM v3 (fallback if ws too small for Apack) ----------
__global__ __launch_bounds__(256) void gcn_mfma(const float* __restrict__ A,
                                                const short* __restrict__ Bpack,
                                                float* __restrict__ C,
                                                int K) {
    int tid = threadIdx.x;
    int lane = tid & 63;
    int wc = tid >> 6;
    int quad = lane >> 4;
    int nl = lane & 15;
    int mrow = blockIdx.x * 16 + nl;
    int kbase = blockIdx.y * KLEN;

    const float* ap = A + (size_t)mrow * K + kbase + quad * 8;
    const short* bp = Bpack + ((size_t)(kbase >> 5)) * 4096
                      + ((size_t)(wc * 32 + nl) << 5) + quad * 8;
    const int NP = KLEN >> 6;

    f32x4 acc0 = {0.f, 0.f, 0.f, 0.f};
    f32x4 acc1 = {0.f, 0.f, 0.f, 0.f};

    auto loadA = [&](int p, int h) {
        return *(const f32x8*)(ap + (size_t)(2 * p + h) * 32);
    };
    auto loadB = [&](int p, int h, int t) {
        return *(const bf16x8*)(bp + (size_t)(2 * p + h) * 4096 + t * 512);
    };

    f32x8 a0A = loadA(0, 0), a0B = loadA(0, 1);
    f32x8 a1A = loadA(1, 0), a1B = loadA(1, 1);
    bf16x8 b00 = loadB(0, 0, 0), b01 = loadB(0, 0, 1);
    bf16x8 b10 = loadB(0, 1, 0), b11 = loadB(0, 1, 1);

    for (int p = 0; p < NP; ++p) {
        int pn2 = p + 2 < NP ? p + 2 : NP - 1;
        int pn1 = p + 1 < NP ? p + 1 : NP - 1;
        f32x8 a2A = loadA(pn2, 0), a2B = loadA(pn2, 1);
        bf16x8 nb00 = loadB(pn1, 0, 0), nb01 = loadB(pn1, 0, 1);
        bf16x8 nb10 = loadB(pn1, 1, 0), nb11 = loadB(pn1, 1, 1);

        bf16x8 af;
#pragma unroll
        for (int i = 0; i < 8; ++i) af[i] = f2bf(a0A[i]);
        acc0 = __builtin_amdgcn_mfma_f32_16x16x32_bf16(af, b00, acc0, 0, 0, 0);
        acc1 = __builtin_amdgcn_mfma_f32_16x16x32_bf16(af, b01, acc1, 0, 0, 0);
#pragma unroll
        for (int i = 0; i < 8; ++i) af[i] = f2bf(a0B[i]);
        acc0 = __builtin_amdgcn_mfma_f32_16x16x32_bf16(af, b10, acc0, 0, 0, 0);
        acc1 = __builtin_amdgcn_mfma_f32_16x16x32_bf16(af, b11, acc1, 0, 0, 0);

        a0A = a1A; a0B = a1B; a1A = a2A; a1B = a2B;
        b00 = nb00; b01 = nb01; b10 = nb10; b11 = nb11;
    }

    int rbase = blockIdx.x * 16 + quad * 4;
    int cbase = wc * 32 + nl;
#pragma unroll
    for (int t = 0; t < 2; ++t) {
        int col = cbase + t * 16;
        f32x4 a = (t == 0) ? acc0 : acc1;
#pragma unroll
        for (int reg = 0; reg < 4; ++reg)
            atomicAdd(&C[(size_t)(rbase + reg) * 128 + col], a[reg]);
    }
}

// ---------------- GAT helper kernels ----------------
__global__ void eler_kernel(const float* __restrict__ z, const float* __restrict__ al,
                            const float* __restrict__ ar, float* __restrict__ el,
                            float* __restrict__ er, int nNodes, int heads, int dim) {
    int idx = blockIdx.x * blockDim.x + threadIdx.x;
    if (idx >= nNodes * heads) return;
    int n = idx / heads, h = idx % heads;
    const float* zp = z + ((size_t)n * heads + h) * dim;
    const float* alp = al + (size_t)h * dim;
    const float* arp = ar + (size_t)h * dim;
    float sl = 0.f, sr = 0.f;
    for (int d = 0; d < dim; ++d) {
        sl = fmaf(zp[d], alp[d], sl);
        sr = fmaf(zp[d], arp[d], sr);
    }
    el[idx] = sl;
    er[idx] = sr;
}

__global__ void edge_max_kernel(const int* __restrict__ src, const int* __restrict__ dst,
                                const float* __restrict__ el, const float* __restrict__ er,
                                float* __restrict__ ebuf, unsigned* __restrict__ mkey,
                                int E, int heads) {
    int idx = blockIdx.x * blockDim.x + threadIdx.x;
    if (idx >= E * heads) return;
    int e = idx / heads, h = idx % heads;
    int s = src[e], d = dst[e];
    float x = el[s * heads + h] + er[d * heads + h];
    x = (x > 0.f) ? x : 0.2f * x;
    ebuf[idx] = x;
    atomicMax(&mkey[d * heads + h], fenc(x));
}

__global__ void edge_exp_kernel(const int* __restrict__ dst, float* __restrict__ ebuf,
                                const unsigned* __restrict__ mkey, float* __restrict__ ssum,
                                int E, int heads) {
    int idx = blockIdx.x * blockDim.x + threadIdx.x;
    if (idx >= E * heads) return;
    int e = idx / heads, h = idx % heads;
    int d = dst[e];
    float m = fdec(mkey[d * heads + h]);
    float ex = expf(ebuf[idx] - m);
    ebuf[idx] = ex;
    atomicAdd(&ssum[d * heads + h], ex);
}

// agg[dst] += z[src] * (ex / s[dst])
__global__ void edge_msg_kernel(const int* __restrict__ src, const int* __restrict__ dst,
                                const float* __restrict__ z, const float* __restrict__ ebuf,
                                const float* __restrict__ ssum,
                                float* __restrict__ agg, int E, int heads, int dim) {
    int idx = blockIdx.x * blockDim.x + threadIdx.x;
    int HD = heads * dim;
    if (idx >= E * HD) return;
    int e = idx / HD;
    int j = idx % HD;
    int h = j / dim;
    int d = dst[e];
    float coef = ebuf[e * heads + h] / ssum[d * heads + h];
    float v = z[(size_t)src[e] * HD + j] * coef;
    atomicAdd(&agg[(size_t)d * HD + j], v);
}

__global__ void bias_act_kernel(const float* __restrict__ in, const float* __restrict__ bias,
                                float* __restrict__ out, int n, int cols, int relu) {
    int idx = blockIdx.x * blockDim.x + threadIdx.x;
    if (idx >= n) return;
    float v = in[idx] + bias[idx % cols];
    if (relu) v = fmaxf(v, 0.f);
    out[idx] = v;
}

// ---------------- gather/concat ----------------
__global__ void gather_concat_kernel(const float* __restrict__ tok, const float* __restrict__ inst,
                                     const int* __restrict__ lids, const int* __restrict__ gids,
                                     float* __restrict__ xcat) {
    int bs = blockIdx.x;
    int j = threadIdx.x;
    int g = gids[bs];
    int b = bs / SEQv;
    int l = lids[bs];
    float v;
    if (j < 128) v = tok[(size_t)g * 128 + j];
    else v = inst[(size_t)(b * NCv + l) * 128 + (j - 128)];
    xcat[(size_t)bs * 256 + j] = v;
}

// ---------------- LSTM recurrence v2: Whh rows in registers ----------------
__global__ __launch_bounds__(512) void lstm2_kernel(const float* __restrict__ xW,
                                                    const float* __restrict__ Whh_f,
                                                    const float* __restrict__ Whh_b,
                                                    float* __restrict__ y,
                                                    float* __restrict__ hidden,
                                                    int write_y) {
    int b = blockIdx.x;
    int dir = blockIdx.y;
    int t = threadIdx.x;
    const float* Whh = dir ? Whh_b : Whh_f;
    const float* xw = xW + ((size_t)dir * Bv * SEQv + (size_t)b * SEQv) * 400;

    __shared__ float hsh[104];
    __shared__ float gsh[400];

    float w[100];
    if (t < 400) {
        const float* wr = Whh + (size_t)t * 100;
#pragma unroll
        for (int j = 0; j < 100; j += 4) {
            float4 v = *(const float4*)(wr + j);
            w[j] = v.x; w[j + 1] = v.y; w[j + 2] = v.z; w[j + 3] = v.w;
        }
    }
    if (t < 104) hsh[t] = 0.f;
    float c = 0.f;
    __syncthreads();

    for (int it = 0; it < SEQv; ++it) {
        int tt = dir ? (SEQv - 1 - it) : it;
        if (t < 400) {
            float a0 = 0.f, a1 = 0.f, a2 = 0.f, a3 = 0.f;
#pragma unroll
            for (int k = 0; k < 100; k += 4) {
                a0 = fmaf(w[k], hsh[k], a0);
                a1 = fmaf(w[k + 1], hsh[k + 1], a1);
                a2 = fmaf(w[k + 2], hsh[k + 2], a2);
                a3 = fmaf(w[k + 3], hsh[k + 3], a3);
            }
            gsh[t] = xw[tt * 400 + t] + ((a0 + a1) + (a2 + a3));
        }
        __syncthreads();
        if (t < Hv) {
            float gi = gsh[t], gf = gsh[Hv + t], gg = gsh[2 * Hv + t], go = gsh[3 * Hv + t];
            float si = 1.f / (1.f + expf(-gi));
            float sf = 1.f / (1.f + expf(-gf));
            float so = 1.f / (1.f + expf(-go));
            float tg = tanhf(gg);
            c = sf * c + si * tg;
            float h = so * tanhf(c);
            hsh[t] = h;
            if (write_y) y[((size_t)b * SEQv + tt) * 200 + dir * Hv + t] = h;
        }
        __syncthreads();
    }
    if (!write_y && t < Hv) hidden[b * 200 + dir * Hv + t] = hsh[t];
}

// ---------------- final FC ----------------
__global__ void fc_kernel(const float* __restrict__ hidden, const float* __restrict__ W,
                          const float* __restrict__ bias, float* __restrict__ out) {
    int idx = threadIdx.x;
    if (idx >= Bv * CLSv) return;
    int b = idx >> 2, c = idx & 3;
    float s = bias[c];
    for (int j = 0; j < 200; ++j) s = fmaf(hidden[b * 200 + j], W[j * 4 + c], s);
    out[idx] = s;
}

// ============================================================================
extern "C" void kernel_launch(void* const* d_in, const int* in_sizes, int n_in,
                              void* d_out, int out_size, void* d_ws, size_t ws_size,
                              hipStream_t stream) {
    const float* emb      = (const float*)d_in[0];
    const float* tg       = (const float*)d_in[1];
    const float* tokemb   = (const float*)d_in[2];
    const float* gcn_W1   = (const float*)d_in[3];
    const float* gcn_b1   = (const float*)d_in[4];
    const float* gcn_W2   = (const float*)d_in[5];
    const float* gcn_b2   = (const float*)d_in[6];
    const float* gat1_W   = (const float*)d_in[7];
    const float* gat1_al  = (const float*)d_in[8];
    const float* gat1_ar  = (const float*)d_in[9];
    const float* gat1_b   = (const float*)d_in[10];
    const float* gat2_W   = (const float*)d_in[11];
    const float* gat2_al  = (const float*)d_in[12];
    const float* gat2_ar  = (const float*)d_in[13];
    const float* gat2_b   = (const float*)d_in[14];
    const float* l0f_Wih  = (const float*)d_in[15];
    const float* l0f_Whh  = (const float*)d_in[16];
    const float* l0f_b    = (const float*)d_in[17];
    const float* l0b_Wih  = (const float*)d_in[18];
    const float* l0b_Whh  = (const float*)d_in[19];
    const float* l0b_b    = (const float*)d_in[20];
    const float* l1f_Wih  = (const float*)d_in[21];
    const float* l1f_Whh  = (const float*)d_in[22];
    const float* l1f_b    = (const float*)d_in[23];
    const float* l1b_Wih  = (const float*)d_in[24];
    const float* l1b_Whh  = (const float*)d_in[25];
    const float* l1b_b    = (const float*)d_in[26];
    const float* fc_W     = (const float*)d_in[27];
    const float* fc_b     = (const float*)d_in[28];
    const int*   src      = (const int*)d_in[29];
    const int*   dst      = (const int*)d_in[30];
    const int*   lids     = (const int*)d_in[31];
    const int*   gids     = (const int*)d_in[32];
    const int E = in_sizes[29];   // 11520

    float* ws = (float*)d_ws;
    size_t off = 0;
    auto alloc = [&](size_t n) { float* p = ws + off; off += n; return p; };

    // ---- zero-initialized region (single memset) ----
    float* m1   = alloc((size_t)NTv * HEADSv);
    float* s1   = alloc((size_t)NTv * HEADSv);
    float* agg1 = alloc((size_t)NTv * 512);
    float* m2   = alloc(NTv);
    float* s2   = alloc(NTv);
    float* agg2 = alloc((size_t)NTv * 128);
    float* T    = alloc((size_t)NTOKv * 128);   // atomic accumulate targets
    float* tok  = alloc((size_t)NTOKv * 128);
    size_t zeroFloats = off;

    float* z1   = alloc((size_t)NTv * 512);
    float* el1  = alloc((size_t)NTv * HEADSv);
    float* er1  = alloc((size_t)NTv * HEADSv);
    float* ebuf = alloc((size_t)E * HEADSv);
    float* h1   = alloc((size_t)NTv * 512);
    float* z2   = alloc((size_t)NTv * 128);
    float* el2  = alloc(NTv);
    float* er2  = alloc(NTv);
    float* inst = alloc((size_t)NTv * 128);
    float* P    = alloc((size_t)NTOKv * 128);
    float* Q    = alloc((size_t)NTOKv * 128);
    float* xcat = alloc((size_t)Bv * SEQv * 256);
    float* xw0  = alloc((size_t)2 * Bv * SEQv * 400);
    float* y    = alloc((size_t)Bv * SEQv * 200);
    float* xw1  = alloc((size_t)2 * Bv * SEQv * 400);
    float* hidden = alloc((size_t)Bv * 200);
    short* Ppack = (short*)alloc((size_t)NTOKv * 128 / 2);
    short* Qpack = (short*)alloc((size_t)NTOKv * 128 / 2);
    short* Apack = (short*)alloc((size_t)NTOKv * NTOKv / 2);   // 128 MB, last
    bool useApack = (off * sizeof(float)) <= ws_size;

    hipMemsetAsync(d_ws, 0, zeroFloats * sizeof(float), stream);

    // ================= A pre-pack (once, reused by both token GEMMs) ========
    if (useApack)
        pack_a_kernel<<<(NTOKv * (NTOKv / 8)) / 256, 256, 0, stream>>>(tg, Apack);

    // ================= GAT layer 1 =================
    {
        dim3 g(512 / BN, NTv / BM);
        gemm_nn<<<g, 256, 0, stream>>>(emb, gat1_W, nullptr, z1, NTv, 512, INv, 0);
    }
    eler_kernel<<<(NTv * HEADSv + 255) / 256, 256, 0, stream>>>(z1, gat1_al, gat1_ar, el1, er1, NTv, HEADSv, 128);
    {
        int n = E * HEADSv, blocks = (n + 255) / 256;
        edge_max_kernel<<<blocks, 256, 0, stream>>>(src, dst, el1, er1, ebuf, (unsigned*)m1, E, HEADSv);
        edge_exp_kernel<<<blocks, 256, 0, stream>>>(dst, ebuf, (const unsigned*)m1, s1, E, HEADSv);
        int n2 = E * 512;
        edge_msg_kernel<<<(n2 + 255) / 256, 256, 0, stream>>>(src, dst, z1, ebuf, s1, agg1, E, HEADSv, 128);
    }
    bias_act_kernel<<<(NTv * 512 + 255) / 256, 256, 0, stream>>>(agg1, gat1_b, h1, NTv * 512, 512, 1);

    // ================= GAT layer 2 =================
    {
        dim3 g(128 / BN, NTv / BM);
        gemm_nn<<<g, 256, 0, stream>>>(h1, gat2_W, nullptr, z2, NTv, 128, 512, 0);
    }
    eler_kernel<<<(NTv + 255) / 256, 256, 0, stream>>>(z2, gat2_al, gat2_ar, el2, er2, NTv, 1, 128);
    {
        int n = E, blocks = (n + 255) / 256;
        edge_max_kernel<<<blocks, 256, 0, stream>>>(src, dst, el2, er2, ebuf, (unsigned*)m2, E, 1);
        edge_exp_kernel<<<blocks, 256, 0, stream>>>(dst, ebuf, (const unsigned*)m2, s2, E, 1);
        int n2 = E * 128;
        edge_msg_kernel<<<(n2 + 255) / 256, 256, 0, stream>>>(src, dst, z2, ebuf, s2, agg2, E, 1, 128);
    }
    bias_act_kernel<<<(NTv * 128 + 255) / 256, 256, 0, stream>>>(agg2, gat2_b, inst, NTv * 128, 128, 0);

    // ================= GCN (token graph) — MFMA K-split path =================
    {
        dim3 g(128 / BN, NTOKv / BM);
        gemm_nn<<<g, 256, 0, stream>>>(tokemb, gcn_W1, nullptr, P, NTOKv, 128, INv, 0);
        pack_b_kernel<<<NTOKv / 32, 256, 0, stream>>>(P, Ppack);
        if (useApack) {
            dim3 gg(NTOKv / 32, KSPLIT);
            gcn_mfma5<<<gg, 256, 0, stream>>>(Apack, Ppack, T);
        } else {
            dim3 gg(NTOKv / 16, KSPLIT);
            gcn_mfma<<<gg, 256, 0, stream>>>(tg, Ppack, T, NTOKv);
        }
        bias_act_kernel<<<(NTOKv * 128 + 255) / 256, 256, 0, stream>>>(T, gcn_b1, T, NTOKv * 128, 128, 1);
        gemm_nn<<<g, 256, 0, stream>>>(T, gcn_W2, nullptr, Q, NTOKv, 128, 128, 0);
        pack_b_kernel<<<NTOKv / 32, 256, 0, stream>>>(Q, Qpack);
        if (useApack) {
            dim3 gg(NTOKv / 32, KSPLIT);
            gcn_mfma5<<<gg, 256, 0, stream>>>(Apack, Qpack, tok);
        } else {
            dim3 gg(NTOKv / 16, KSPLIT);
            gcn_mfma<<<gg, 256, 0, stream>>>(tg, Qpack, tok, NTOKv);
        }
        bias_act_kernel<<<(NTOKv * 128 + 255) / 256, 256, 0, stream>>>(tok, gcn_b2, tok, NTOKv * 128, 128, 0);
    }

    // ================= gather/concat =================
    gather_concat_kernel<<<Bv * SEQv, 256, 0, stream>>>(tok, inst, lids, gids, xcat);

    // ================= LSTM layer 0 =================
    {
        dim3 g((400 + BN - 1) / BN, (Bv * SEQv) / BM);
        gemm_nt<<<g, 256, 0, stream>>>(xcat, l0f_Wih, l0f_b, xw0, Bv * SEQv, 400, 256);
        gemm_nt<<<g, 256, 0, stream>>>(xcat, l0b_Wih, l0b_b, xw0 + (size_t)Bv * SEQv * 400, Bv * SEQv, 400, 256);
    }
    {
        dim3 g(Bv, 2);
        lstm2_kernel<<<g, 512, 0, stream>>>(xw0, l0f_Whh, l0b_Whh, y, nullptr, 1);
    }

    // ================= LSTM layer 1 =================
    {
        dim3 g((400 + BN - 1) / BN, (Bv * SEQv) / BM);
        gemm_nt<<<g, 256, 0, stream>>>(y, l1f_Wih, l1f_b, xw1, Bv * SEQv, 400, 200);
        gemm_nt<<<g, 256, 0, stream>>>(y, l1b_Wih, l1b_b, xw1 + (size_t)Bv * SEQv * 400, Bv * SEQv, 400, 200);
    }
    {
        dim3 g(Bv, 2);
        lstm2_kernel<<<g, 512, 0, stream>>>(xw1, l1f_Whh, l1b_Whh, nullptr, hidden, 0);
    }

    // ================= FC head =================
    fc_kernel<<<1, 128, 0, stream>>>(hidden, fc_W, fc_b, (float*)d_out);
}

// Round 7
// 1171.849 us; speedup vs baseline: 1.1919x; 1.0923x over previous
//
#include <hip/hip_runtime.h>
#include <math.h>

// Problem constants
#define NTOKv   8000
#define INv     300
#define HIDv    128
#define HEADSv  4
#define OUTv    128
#define CLSv    4
#define Bv      32
#define NCv     40
#define SEQv    60
#define NTv     1280   // B*NC
#define Hv      100
#define BSv     1920   // B*SEQ

#define KSPLIT  5
#define KLEN    1600            // 8000 / KSPLIT
#define NCHUNK  (KLEN / 32)     // 50

typedef __attribute__((ext_vector_type(8))) short bf16x8;
typedef __attribute__((ext_vector_type(4))) float f32x4;
typedef __attribute__((ext_vector_type(8))) float f32x8;

// ---------------- ordered-float encoding for atomicMax on unsigned ----------
__device__ __forceinline__ unsigned fenc(float f) {
    unsigned u = __float_as_uint(f);
    return (u & 0x80000000u) ? ~u : (u | 0x80000000u);
}
__device__ __forceinline__ float fdec(unsigned u) {
    return (u & 0x80000000u) ? __uint_as_float(u ^ 0x80000000u) : __uint_as_float(~u);
}

__device__ __forceinline__ short f2bf(float f) {
    unsigned u = __float_as_uint(f);
    u = u + 0x7FFFu + ((u >> 16) & 1u);   // RNE
    return (short)(u >> 16);
}

// ---------------- generic tiled fp32 GEMM: C = A(MxK) @ B(KxN) (+bias)(+relu)
#define BM 64
#define BN 64
#define BK 16
__global__ __launch_bounds__(256) void gemm_nn(const float* __restrict__ A,
                                               const float* __restrict__ B,
                                               const float* __restrict__ bias,
                                               float* __restrict__ C,
                                               int M, int N, int K, int relu) {
    __shared__ float As[BK][BM + 4];
    __shared__ float Bs[BK][BN + 4];
    int tid = threadIdx.x;
    int bn = blockIdx.x * BN, bm = blockIdx.y * BM;
    int tx = tid & 15, ty = tid >> 4;
    float acc[4][4] = {};
    for (int k0 = 0; k0 < K; k0 += BK) {
#pragma unroll
        for (int i = 0; i < 4; ++i) {
            int t = tid + i * 256;
            int m = t >> 4, kk = t & 15;
            float v = 0.f;
            if ((bm + m) < M && (k0 + kk) < K) v = A[(size_t)(bm + m) * K + k0 + kk];
            As[kk][m] = v;
        }
#pragma unroll
        for (int i = 0; i < 4; ++i) {
            int t = tid + i * 256;
            int kk = t >> 6, n = t & 63;
            float v = 0.f;
            if ((k0 + kk) < K && (bn + n) < N) v = B[(size_t)(k0 + kk) * N + bn + n];
            Bs[kk][n] = v;
        }
        __syncthreads();
#pragma unroll
        for (int kk = 0; kk < BK; ++kk) {
            float a[4], b[4];
#pragma unroll
            for (int r = 0; r < 4; ++r) a[r] = As[kk][ty * 4 + r];
#pragma unroll
            for (int c = 0; c < 4; ++c) b[c] = Bs[kk][tx * 4 + c];
#pragma unroll
            for (int r = 0; r < 4; ++r)
#pragma unroll
                for (int c = 0; c < 4; ++c) acc[r][c] = fmaf(a[r], b[c], acc[r][c]);
        }
        __syncthreads();
    }
#pragma unroll
    for (int r = 0; r < 4; ++r) {
        int m = bm + ty * 4 + r;
        if (m >= M) continue;
#pragma unroll
        for (int c = 0; c < 4; ++c) {
            int n = bn + tx * 4 + c;
            if (n >= N) continue;
            float v = acc[r][c];
            if (bias) v += bias[n];
            if (relu) v = fmaxf(v, 0.f);
            C[(size_t)m * N + n] = v;
        }
    }
}

// C[z] = A(MxK) @ Bz(NxK)^T + bias_z; grid.z in {0,1} picks (B0,bias0)/(B1,bias1)
__global__ __launch_bounds__(256) void gemm_nt2(const float* __restrict__ A,
                                                const float* __restrict__ B0w,
                                                const float* __restrict__ B1w,
                                                const float* __restrict__ bias0,
                                                const float* __restrict__ bias1,
                                                float* __restrict__ Cbase,
                                                int M, int N, int K, int strideC) {
    const float* B = blockIdx.z ? B1w : B0w;
    const float* bias = blockIdx.z ? bias1 : bias0;
    float* C = Cbase + (size_t)blockIdx.z * strideC;
    __shared__ float As[BK][BM + 4];
    __shared__ float Bs[BK][BN + 4];
    int tid = threadIdx.x;
    int bn = blockIdx.x * BN, bm = blockIdx.y * BM;
    int tx = tid & 15, ty = tid >> 4;
    float acc[4][4] = {};
    for (int k0 = 0; k0 < K; k0 += BK) {
#pragma unroll
        for (int i = 0; i < 4; ++i) {
            int t = tid + i * 256;
            int m = t >> 4, kk = t & 15;
            float v = 0.f;
            if ((bm + m) < M && (k0 + kk) < K) v = A[(size_t)(bm + m) * K + k0 + kk];
            As[kk][m] = v;
        }
#pragma unroll
        for (int i = 0; i < 4; ++i) {
            int t = tid + i * 256;
            int n = t >> 4, kk = t & 15;
            float v = 0.f;
            if ((bn + n) < N && (k0 + kk) < K) v = B[(size_t)(bn + n) * K + k0 + kk];
            Bs[kk][n] = v;
        }
        __syncthreads();
#pragma unroll
        for (int kk = 0; kk < BK; ++kk) {
            float a[4], b[4];
#pragma unroll
            for (int r = 0; r < 4; ++r) a[r] = As[kk][ty * 4 + r];
#pragma unroll
            for (int c = 0; c < 4; ++c) b[c] = Bs[kk][tx * 4 + c];
#pragma unroll
            for (int r = 0; r < 4; ++r)
#pragma unroll
                for (int c = 0; c < 4; ++c) acc[r][c] = fmaf(a[r], b[c], acc[r][c]);
        }
        __syncthreads();
    }
#pragma unroll
    for (int r = 0; r < 4; ++r) {
        int m = bm + ty * 4 + r;
        if (m >= M) continue;
#pragma unroll
        for (int c = 0; c < 4; ++c) {
            int n = bn + tx * 4 + c;
            if (n >= N) continue;
            float v = acc[r][c];
            if (bias) v += bias[n];
            C[(size_t)m * N + n] = v;
        }
    }
}

// ---------------- pack B (KxN=128 fp32, row-major) -> bf16 frag layout -------
// out[(kc*128 + n)*32 + r] = bf16(B[kc*32 + r][n])
__global__ __launch_bounds__(256) void pack_b_kernel(const float* __restrict__ B,
                                                     short* __restrict__ out) {
    __shared__ float sh[32 * 129];
    int kc = blockIdx.x;
    int tid = threadIdx.x;
    const float* src = B + (size_t)kc * 4096;
    for (int i = tid; i < 4096; i += 256)
        sh[(i >> 7) * 129 + (i & 127)] = src[i];
    __syncthreads();
    short* op = out + (size_t)kc * 4096;
    for (int i = tid; i < 4096; i += 256) {
        int n = i >> 5, r = i & 31;
        op[i] = f2bf(sh[r * 129 + n]);
    }
}

// ---------------- pack A (tg, 8000x8000 fp32) -> bf16 A-frag layout ----------
// out[((k/32)*8000 + m)*32 + (k%32)] = bf16(A[m][k]); 8 k's per thread.
__global__ __launch_bounds__(256) void pack_a_kernel(const float* __restrict__ A,
                                                     short* __restrict__ out) {
    size_t gid = (size_t)blockIdx.x * 256 + threadIdx.x;   // 8M total
    int q = (int)(gid & 3);
    size_t rest = gid >> 2;
    int m = (int)(rest % 8000);
    int kc = (int)(rest / 8000);
    const float* src = A + (size_t)m * 8000 + kc * 32 + q * 8;
    f32x8 v = *(const f32x8*)src;
    bf16x8 o;
#pragma unroll
    for (int i = 0; i < 8; ++i) o[i] = f2bf(v[i]);
    *(bf16x8*)(out + ((size_t)kc * 8000 + m) * 32 + q * 8) = o;
}

// ---------------- MFMA GEMM v5: pre-packed bf16 A and B, K-split atomics -----
// grid (250, KSPLIT). 32 rows x 128 cols per block; 4 waves = 4 col strips.
__global__ __launch_bounds__(256) void gcn_mfma5(const short* __restrict__ Apack,
                                                 const short* __restrict__ Bpack,
                                                 float* __restrict__ C) {
    int tid = threadIdx.x;
    int lane = tid & 63;
    int wc = tid >> 6;
    int quad = lane >> 4;
    int nl = lane & 15;
    int m0 = blockIdx.x * 32;
    int kc0 = blockIdx.y * NCHUNK;

    const short* apA = Apack + ((size_t)kc0 * 8000 + m0 + nl) * 32 + quad * 8;
    const short* apB = apA + 16 * 32;
    const short* bp0 = Bpack + ((size_t)kc0 * 128 + wc * 32 + nl) * 32 + quad * 8;
    const short* bp1 = bp0 + 16 * 32;

    f32x4 acc00 = {0.f, 0.f, 0.f, 0.f};
    f32x4 acc01 = acc00, acc10 = acc00, acc11 = acc00;

    auto lA0 = [&](int c) { return *(const bf16x8*)(apA + (size_t)c * 256000); };
    auto lA1 = [&](int c) { return *(const bf16x8*)(apB + (size_t)c * 256000); };
    auto lB0 = [&](int c) { return *(const bf16x8*)(bp0 + (size_t)c * 4096); };
    auto lB1 = [&](int c) { return *(const bf16x8*)(bp1 + (size_t)c * 4096); };

    bf16x8 a00 = lA0(0), a10 = lA1(0), b00 = lB0(0), b10 = lB1(0);
    bf16x8 a01 = lA0(1), a11 = lA1(1), b01 = lB0(1), b11 = lB1(1);

    for (int c = 0; c < NCHUNK; ++c) {
        int cn = c + 2 < NCHUNK ? c + 2 : NCHUNK - 1;
        bf16x8 na0 = lA0(cn), na1 = lA1(cn), nb0 = lB0(cn), nb1 = lB1(cn);

        acc00 = __builtin_amdgcn_mfma_f32_16x16x32_bf16(a00, b00, acc00, 0, 0, 0);
        acc01 = __builtin_amdgcn_mfma_f32_16x16x32_bf16(a00, b10, acc01, 0, 0, 0);
        acc10 = __builtin_amdgcn_mfma_f32_16x16x32_bf16(a10, b00, acc10, 0, 0, 0);
        acc11 = __builtin_amdgcn_mfma_f32_16x16x32_bf16(a10, b10, acc11, 0, 0, 0);

        a00 = a01; a10 = a11; b00 = b01; b10 = b11;
        a01 = na0; a11 = na1; b01 = nb0; b11 = nb1;
    }

    int rb0 = m0 + quad * 4;
    int rb1 = rb0 + 16;
    int c0 = wc * 32 + nl;
    int c1 = c0 + 16;
#pragma unroll
    for (int reg = 0; reg < 4; ++reg) {
        atomicAdd(&C[(size_t)(rb0 + reg) * 128 + c0], acc00[reg]);
        atomicAdd(&C[(size_t)(rb0 + reg) * 128 + c1], acc01[reg]);
        atomicAdd(&C[(size_t)(rb1 + reg) * 128 + c0], acc10[reg]);
        atomicAdd(&C[(size_t)(rb1 + reg) * 128 + c1], acc11[reg]);
    }
}

// ---------------- MFMA GEMM gathered: only rows gids[0..1919] ----------------
// grid (BSv/32, KSPLIT). Virtual row vr -> A row gids[vr]; output Cg[vr][128].
__global__ __launch_bounds__(256) void gcn_mfma_g(const short* __restrict__ Apack,
                                                  const short* __restrict__ Bpack,
                                                  const int* __restrict__ gids,
                                                  float* __restrict__ Cg) {
    int tid = threadIdx.x;
    int lane = tid & 63;
    int wc = tid >> 6;
    int quad = lane >> 4;
    int nl = lane & 15;
    int m0 = blockIdx.x * 32;
    int kc0 = blockIdx.y * NCHUNK;

    int gA = gids[m0 + nl];
    int gB = gids[m0 + 16 + nl];

    const short* apA = Apack + ((size_t)kc0 * 8000 + gA) * 32 + quad * 8;
    const short* apB = Apack + ((size_t)kc0 * 8000 + gB) * 32 + quad * 8;
    const short* bp0 = Bpack + ((size_t)kc0 * 128 + wc * 32 + nl) * 32 + quad * 8;
    const short* bp1 = bp0 + 16 * 32;

    f32x4 acc00 = {0.f, 0.f, 0.f, 0.f};
    f32x4 acc01 = acc00, acc10 = acc00, acc11 = acc00;

    auto lA0 = [&](int c) { return *(const bf16x8*)(apA + (size_t)c * 256000); };
    auto lA1 = [&](int c) { return *(const bf16x8*)(apB + (size_t)c * 256000); };
    auto lB0 = [&](int c) { return *(const bf16x8*)(bp0 + (size_t)c * 4096); };
    auto lB1 = [&](int c) { return *(const bf16x8*)(bp1 + (size_t)c * 4096); };

    bf16x8 a00 = lA0(0), a10 = lA1(0), b00 = lB0(0), b10 = lB1(0);
    bf16x8 a01 = lA0(1), a11 = lA1(1), b01 = lB0(1), b11 = lB1(1);

    for (int c = 0; c < NCHUNK; ++c) {
        int cn = c + 2 < NCHUNK ? c + 2 : NCHUNK - 1;
        bf16x8 na0 = lA0(cn), na1 = lA1(cn), nb0 = lB0(cn), nb1 = lB1(cn);

        acc00 = __builtin_amdgcn_mfma_f32_16x16x32_bf16(a00, b00, acc00, 0, 0, 0);
        acc01 = __builtin_amdgcn_mfma_f32_16x16x32_bf16(a00, b10, acc01, 0, 0, 0);
        acc10 = __builtin_amdgcn_mfma_f32_16x16x32_bf16(a10, b00, acc10, 0, 0, 0);
        acc11 = __builtin_amdgcn_mfma_f32_16x16x32_bf16(a10, b10, acc11, 0, 0, 0);

        a00 = a01; a10 = a11; b00 = b01; b10 = b11;
        a01 = na0; a11 = na1; b01 = nb0; b11 = nb1;
    }

    int rb0 = m0 + quad * 4;
    int rb1 = rb0 + 16;
    int c0 = wc * 32 + nl;
    int c1 = c0 + 16;
#pragma unroll
    for (int reg = 0; reg < 4; ++reg) {
        atomicAdd(&Cg[(size_t)(rb0 + reg) * 128 + c0], acc00[reg]);
        atomicAdd(&Cg[(size_t)(rb0 + reg) * 128 + c1], acc01[reg]);
        atomicAdd(&Cg[(size_t)(rb1 + reg) * 128 + c0], acc10[reg]);
        atomicAdd(&Cg[(size_t)(rb1 + reg) * 128 + c1], acc11[reg]);
    }
}

// ---------------- GAT helper kernels ----------------
__global__ void eler_kernel(const float* __restrict__ z, const float* __restrict__ al,
                            const float* __restrict__ ar, float* __restrict__ el,
                            float* __restrict__ er, int nNodes, int heads, int dim) {
    int idx = blockIdx.x * blockDim.x + threadIdx.x;
    if (idx >= nNodes * heads) return;
    int n = idx / heads, h = idx % heads;
    const float* zp = z + ((size_t)n * heads + h) * dim;
    const float* alp = al + (size_t)h * dim;
    const float* arp = ar + (size_t)h * dim;
    float sl = 0.f, sr = 0.f;
    for (int d = 0; d < dim; ++d) {
        sl = fmaf(zp[d], alp[d], sl);
        sr = fmaf(zp[d], arp[d], sr);
    }
    el[idx] = sl;
    er[idx] = sr;
}

__global__ void edge_max_kernel(const int* __restrict__ src, const int* __restrict__ dst,
                                const float* __restrict__ el, const float* __restrict__ er,
                                float* __restrict__ ebuf, unsigned* __restrict__ mkey,
                                int E, int heads) {
    int idx = blockIdx.x * blockDim.x + threadIdx.x;
    if (idx >= E * heads) return;
    int e = idx / heads, h = idx % heads;
    int s = src[e], d = dst[e];
    float x = el[s * heads + h] + er[d * heads + h];
    x = (x > 0.f) ? x : 0.2f * x;
    ebuf[idx] = x;
    atomicMax(&mkey[d * heads + h], fenc(x));
}

__global__ void edge_exp_kernel(const int* __restrict__ dst, float* __restrict__ ebuf,
                                const unsigned* __restrict__ mkey, float* __restrict__ ssum,
                                int E, int heads) {
    int idx = blockIdx.x * blockDim.x + threadIdx.x;
    if (idx >= E * heads) return;
    int e = idx / heads, h = idx % heads;
    int d = dst[e];
    float m = fdec(mkey[d * heads + h]);
    float ex = expf(ebuf[idx] - m);
    ebuf[idx] = ex;
    atomicAdd(&ssum[d * heads + h], ex);
}

// agg[dst] += z[src] * (ex / s[dst])
__global__ void edge_msg_kernel(const int* __restrict__ src, const int* __restrict__ dst,
                                const float* __restrict__ z, const float* __restrict__ ebuf,
                                const float* __restrict__ ssum,
                                float* __restrict__ agg, int E, int heads, int dim) {
    int idx = blockIdx.x * blockDim.x + threadIdx.x;
    int HD = heads * dim;
    if (idx >= E * HD) return;
    int e = idx / HD;
    int j = idx % HD;
    int h = j / dim;
    int d = dst[e];
    float coef = ebuf[e * heads + h] / ssum[d * heads + h];
    float v = z[(size_t)src[e] * HD + j] * coef;
    atomicAdd(&agg[(size_t)d * HD + j], v);
}

__global__ void bias_act_kernel(const float* __restrict__ in, const float* __restrict__ bias,
                                float* __restrict__ out, int n, int cols, int relu) {
    int idx = blockIdx.x * blockDim.x + threadIdx.x;
    if (idx >= n) return;
    float v = in[idx] + bias[idx % cols];
    if (relu) v = fmaxf(v, 0.f);
    out[idx] = v;
}

// ---------------- gather/concat: x = [tokg[bs]+b2 | inst[b*NC+lid]] ---------
__global__ void gather_concat_kernel(const float* __restrict__ tokg,
                                     const float* __restrict__ b2,
                                     const float* __restrict__ inst,
                                     const int* __restrict__ lids,
                                     float* __restrict__ xcat) {
    int bs = blockIdx.x;
    int j = threadIdx.x;
    int b = bs / SEQv;
    int l = lids[bs];
    float v;
    if (j < 128) v = tokg[(size_t)bs * 128 + j] + b2[j];
    else v = inst[(size_t)(b * NCv + l) * 128 + (j - 128)];
    xcat[(size_t)bs * 256 + j] = v;
}

// ---------------- LSTM recurrence v2: Whh rows in registers ----------------
__global__ __launch_bounds__(512) void lstm2_kernel(const float* __restrict__ xW,
                                                    const float* __restrict__ Whh_f,
                                                    const float* __restrict__ Whh_b,
                                                    float* __restrict__ y,
                                                    float* __restrict__ hidden,
                                                    int write_y) {
    int b = blockIdx.x;
    int dir = blockIdx.y;
    int t = threadIdx.x;
    const float* Whh = dir ? Whh_b : Whh_f;
    const float* xw = xW + ((size_t)dir * Bv * SEQv + (size_t)b * SEQv) * 400;

    __shared__ float hsh[104];
    __shared__ float gsh[400];

    float w[100];
    if (t < 400) {
        const float* wr = Whh + (size_t)t * 100;
#pragma unroll
        for (int j = 0; j < 100; j += 4) {
            float4 v = *(const float4*)(wr + j);
            w[j] = v.x; w[j + 1] = v.y; w[j + 2] = v.z; w[j + 3] = v.w;
        }
    }
    if (t < 104) hsh[t] = 0.f;
    float c = 0.f;
    __syncthreads();

    for (int it = 0; it < SEQv; ++it) {
        int tt = dir ? (SEQv - 1 - it) : it;
        if (t < 400) {
            float a0 = 0.f, a1 = 0.f, a2 = 0.f, a3 = 0.f;
#pragma unroll
            for (int k = 0; k < 100; k += 4) {
                a0 = fmaf(w[k], hsh[k], a0);
                a1 = fmaf(w[k + 1], hsh[k + 1], a1);
                a2 = fmaf(w[k + 2], hsh[k + 2], a2);
                a3 = fmaf(w[k + 3], hsh[k + 3], a3);
            }
            gsh[t] = xw[tt * 400 + t] + ((a0 + a1) + (a2 + a3));
        }
        __syncthreads();
        if (t < Hv) {
            float gi = gsh[t], gf = gsh[Hv + t], gg = gsh[2 * Hv + t], go = gsh[3 * Hv + t];
            float si = 1.f / (1.f + expf(-gi));
            float sf = 1.f / (1.f + expf(-gf));
            float so = 1.f / (1.f + expf(-go));
            float tg = tanhf(gg);
            c = sf * c + si * tg;
            float h = so * tanhf(c);
            hsh[t] = h;
            if (write_y) y[((size_t)b * SEQv + tt) * 200 + dir * Hv + t] = h;
        }
        __syncthreads();
    }
    if (!write_y && t < Hv) hidden[b * 200 + dir * Hv + t] = hsh[t];
}

// ---------------- final FC ----------------
__global__ void fc_kernel(const float* __restrict__ hidden, const float* __restrict__ W,
                          const float* __restrict__ bias, float* __restrict__ out) {
    int idx = threadIdx.x;
    if (idx >= Bv * CLSv) return;
    int b = idx >> 2, c = idx & 3;
    float s = bias[c];
    for (int j = 0; j < 200; ++j) s = fmaf(hidden[b * 200 + j], W[j * 4 + c], s);
    out[idx] = s;
}

// ============================================================================
extern "C" void kernel_launch(void* const* d_in, const int* in_sizes, int n_in,
                              void* d_out, int out_size, void* d_ws, size_t ws_size,
                              hipStream_t stream) {
    const float* emb      = (const float*)d_in[0];
    const float* tg       = (const float*)d_in[1];
    const float* tokemb   = (const float*)d_in[2];
    const float* gcn_W1   = (const float*)d_in[3];
    const float* gcn_b1   = (const float*)d_in[4];
    const float* gcn_W2   = (const float*)d_in[5];
    const float* gcn_b2   = (const float*)d_in[6];
    const float* gat1_W   = (const float*)d_in[7];
    const float* gat1_al  = (const float*)d_in[8];
    const float* gat1_ar  = (const float*)d_in[9];
    const float* gat1_b   = (const float*)d_in[10];
    const float* gat2_W   = (const float*)d_in[11];
    const float* gat2_al  = (const float*)d_in[12];
    const float* gat2_ar  = (const float*)d_in[13];
    const float* gat2_b   = (const float*)d_in[14];
    const float* l0f_Wih  = (const float*)d_in[15];
    const float* l0f_Whh  = (const float*)d_in[16];
    const float* l0f_b    = (const float*)d_in[17];
    const float* l0b_Wih  = (const float*)d_in[18];
    const float* l0b_Whh  = (const float*)d_in[19];
    const float* l0b_b    = (const float*)d_in[20];
    const float* l1f_Wih  = (const float*)d_in[21];
    const float* l1f_Whh  = (const float*)d_in[22];
    const float* l1f_b    = (const float*)d_in[23];
    const float* l1b_Wih  = (const float*)d_in[24];
    const float* l1b_Whh  = (const float*)d_in[25];
    const float* l1b_b    = (const float*)d_in[26];
    const float* fc_W     = (const float*)d_in[27];
    const float* fc_b     = (const float*)d_in[28];
    const int*   src      = (const int*)d_in[29];
    const int*   dst      = (const int*)d_in[30];
    const int*   lids     = (const int*)d_in[31];
    const int*   gids     = (const int*)d_in[32];
    const int E = in_sizes[29];   // 11520

    float* ws = (float*)d_ws;
    size_t off = 0;
    auto alloc = [&](size_t n) { float* p = ws + off; off += n; return p; };

    // ---- zero-initialized region (single memset) ----
    float* m1   = alloc((size_t)NTv * HEADSv);
    float* s1   = alloc((size_t)NTv * HEADSv);
    float* agg1 = alloc((size_t)NTv * 512);
    float* m2   = alloc(NTv);
    float* s2   = alloc(NTv);
    float* agg2 = alloc((size_t)NTv * 128);
    float* T    = alloc((size_t)NTOKv * 128);   // atomic accumulate target
    float* tokg = alloc((size_t)BSv * 128);     // gathered rows accumulate target
    size_t zeroFloats = off;

    float* z1   = alloc((size_t)NTv * 512);
    float* el1  = alloc((size_t)NTv * HEADSv);
    float* er1  = alloc((size_t)NTv * HEADSv);
    float* ebuf = alloc((size_t)E * HEADSv);
    float* h1   = alloc((size_t)NTv * 512);
    float* z2   = alloc((size_t)NTv * 128);
    float* el2  = alloc(NTv);
    float* er2  = alloc(NTv);
    float* inst = alloc((size_t)NTv * 128);
    float* P    = alloc((size_t)NTOKv * 128);
    float* Q    = alloc((size_t)NTOKv * 128);
    float* xcat = alloc((size_t)BSv * 256);
    float* xw0  = alloc((size_t)2 * BSv * 400);
    float* y    = alloc((size_t)BSv * 200);
    float* xw1  = alloc((size_t)2 * BSv * 400);
    float* hidden = alloc((size_t)Bv * 200);
    short* Ppack = (short*)alloc((size_t)NTOKv * 128 / 2);
    short* Qpack = (short*)alloc((size_t)NTOKv * 128 / 2);
    short* Apack = (short*)alloc((size_t)NTOKv * NTOKv / 2);   // 128 MB, last
    (void)ws_size;

    hipMemsetAsync(d_ws, 0, zeroFloats * sizeof(float), stream);

    // ================= A pre-pack (once, reused by both token GEMMs) ========
    pack_a_kernel<<<(NTOKv * (NTOKv / 8)) / 256, 256, 0, stream>>>(tg, Apack);

    // ================= GAT layer 1 =================
    {
        dim3 g(512 / BN, NTv / BM);
        gemm_nn<<<g, 256, 0, stream>>>(emb, gat1_W, nullptr, z1, NTv, 512, INv, 0);
    }
    eler_kernel<<<(NTv * HEADSv + 255) / 256, 256, 0, stream>>>(z1, gat1_al, gat1_ar, el1, er1, NTv, HEADSv, 128);
    {
        int n = E * HEADSv, blocks = (n + 255) / 256;
        edge_max_kernel<<<blocks, 256, 0, stream>>>(src, dst, el1, er1, ebuf, (unsigned*)m1, E, HEADSv);
        edge_exp_kernel<<<blocks, 256, 0, stream>>>(dst, ebuf, (const unsigned*)m1, s1, E, HEADSv);
        int n2 = E * 512;
        edge_msg_kernel<<<(n2 + 255) / 256, 256, 0, stream>>>(src, dst, z1, ebuf, s1, agg1, E, HEADSv, 128);
    }
    bias_act_kernel<<<(NTv * 512 + 255) / 256, 256, 0, stream>>>(agg1, gat1_b, h1, NTv * 512, 512, 1);

    // ================= GAT layer 2 =================
    {
        dim3 g(128 / BN, NTv / BM);
        gemm_nn<<<g, 256, 0, stream>>>(h1, gat2_W, nullptr, z2, NTv, 128, 512, 0);
    }
    eler_kernel<<<(NTv + 255) / 256, 256, 0, stream>>>(z2, gat2_al, gat2_ar, el2, er2, NTv, 1, 128);
    {
        int n = E, blocks = (n + 255) / 256;
        edge_max_kernel<<<blocks, 256, 0, stream>>>(src, dst, el2, er2, ebuf, (unsigned*)m2, E, 1);
        edge_exp_kernel<<<blocks, 256, 0, stream>>>(dst, ebuf, (const unsigned*)m2, s2, E, 1);
        int n2 = E * 128;
        edge_msg_kernel<<<(n2 + 255) / 256, 256, 0, stream>>>(src, dst, z2, ebuf, s2, agg2, E, 1, 128);
    }
    bias_act_kernel<<<(NTv * 128 + 255) / 256, 256, 0, stream>>>(agg2, gat2_b, inst, NTv * 128, 128, 0);

    // ================= GCN (token graph) =================
    {
        dim3 g(128 / BN, NTOKv / BM);
        gemm_nn<<<g, 256, 0, stream>>>(tokemb, gcn_W1, nullptr, P, NTOKv, 128, INv, 0);
        pack_b_kernel<<<NTOKv / 32, 256, 0, stream>>>(P, Ppack);
        dim3 gg(NTOKv / 32, KSPLIT);
        gcn_mfma5<<<gg, 256, 0, stream>>>(Apack, Ppack, T);
        bias_act_kernel<<<(NTOKv * 128 + 255) / 256, 256, 0, stream>>>(T, gcn_b1, T, NTOKv * 128, 128, 1);
        gemm_nn<<<g, 256, 0, stream>>>(T, gcn_W2, nullptr, Q, NTOKv, 128, 128, 0);
        pack_b_kernel<<<NTOKv / 32, 256, 0, stream>>>(Q, Qpack);
        dim3 gg2(BSv / 32, KSPLIT);
        gcn_mfma_g<<<gg2, 256, 0, stream>>>(Apack, Qpack, gids, tokg);
    }

    // ================= gather/concat (bias b2 fused) =================
    gather_concat_kernel<<<BSv, 256, 0, stream>>>(tokg, gcn_b2, inst, lids, xcat);

    // ================= LSTM layer 0 =================
    {
        dim3 g((400 + BN - 1) / BN, BSv / BM, 2);
        gemm_nt2<<<g, 256, 0, stream>>>(xcat, l0f_Wih, l0b_Wih, l0f_b, l0b_b,
                                        xw0, BSv, 400, 256, BSv * 400);
    }
    {
        dim3 g(Bv, 2);
        lstm2_kernel<<<g, 512, 0, stream>>>(xw0, l0f_Whh, l0b_Whh, y, nullptr, 1);
    }

    // ================= LSTM layer 1 =================
    {
        dim3 g((400 + BN - 1) / BN, BSv / BM, 2);
        gemm_nt2<<<g, 256, 0, stream>>>(y, l1f_Wih, l1b_Wih, l1f_b, l1b_b,
                                        xw1, BSv, 400, 200, BSv * 400);
    }
    {
        dim3 g(Bv, 2);
        lstm2_kernel<<<g, 512, 0, stream>>>(xw1, l1f_Whh, l1b_Whh, nullptr, hidden, 0);
    }

    // ================= FC head =================
    fc_kernel<<<1, 128, 0, stream>>>(hidden, fc_W, fc_b, (float*)d_out);
}